// Round 10
// baseline (84.697 us; speedup 1.0000x reference)
//
#include <hip/hip_runtime.h>

#define M_ROWS  4096
#define IN_DIM  512
#define NEURONS 1024
#define OUT_DIM 512

typedef _Float16 f16;
typedef __attribute__((ext_vector_type(8))) _Float16 f16x8;
typedef __attribute__((ext_vector_type(4))) _Float16 f16x4;
typedef __attribute__((ext_vector_type(4))) float    f32x4;

// ===========================================================================
// prep:
//  [0,1024)    x f32 -> xh f16
//  [1024,1536) W1 [512][1024] -> W1t [1024][512] f16
//  [1536,2048) W2 [1024][512] -> W2t [512][1024] f16 (plain transpose)
//  [2048,2108) cpH[n][ii][4] f16 = coeff window + spb (partition of unity)
// ===========================================================================
__global__ __launch_bounds__(256) void prep(
    const float* __restrict__ x,  f16* __restrict__ xh,
    const float* __restrict__ W1, f16* __restrict__ W1t,
    const float* __restrict__ W2, f16* __restrict__ W2t,
    const float* __restrict__ coeff, const float* __restrict__ spb,
    f16* __restrict__ cpH)
{
    __shared__ float S[32][33];
    const int b = blockIdx.x, t = threadIdx.x;
    if (b < 1024) {
        int i = b * 256 + t;
        const float4* p = (const float4*)x;
        float4 a = p[i * 2], c = p[i * 2 + 1];
        f16x8 o = { (f16)a.x, (f16)a.y, (f16)a.z, (f16)a.w,
                    (f16)c.x, (f16)c.y, (f16)c.z, (f16)c.w };
        *(f16x8*)(xh + (size_t)i * 8) = o;
        return;
    }
    if (b < 1536) {                       // W1 transpose -> f16
        const int tile = b - 1024;
        const int tx = tile & 31, ty = tile >> 5;
        const int tr = t >> 3, tc = (t & 7) * 4;
        float4 v = *(const float4*)&W1[(size_t)(ty * 32 + tr) * NEURONS + tx * 32 + tc];
        S[tr][tc + 0] = v.x; S[tr][tc + 1] = v.y;
        S[tr][tc + 2] = v.z; S[tr][tc + 3] = v.w;
        __syncthreads();
        f16x4 o = {(f16)S[tc + 0][tr], (f16)S[tc + 1][tr],
                   (f16)S[tc + 2][tr], (f16)S[tc + 3][tr]};
        *(f16x4*)&W1t[(size_t)(tx * 32 + tr) * IN_DIM + ty * 32 + tc] = o;
        return;
    }
    if (b < 2048) {                       // W2 transpose -> f16 (plain)
        const int tile = b - 1536;
        const int nt = tile & 15, kt2 = tile >> 4;
        const int tr = t >> 3, tc = (t & 7) * 4;
        float4 v = *(const float4*)&W2[(size_t)(kt2 * 32 + tr) * OUT_DIM + nt * 32 + tc];
        S[tr][tc + 0] = v.x; S[tr][tc + 1] = v.y;
        S[tr][tc + 2] = v.z; S[tr][tc + 3] = v.w;
        __syncthreads();
        f16x4 o = {(f16)S[tc + 0][tr], (f16)S[tc + 1][tr],
                   (f16)S[tc + 2][tr], (f16)S[tc + 3][tr]};
        *(f16x4*)&W2t[(size_t)(nt * 32 + tr) * NEURONS + kt2 * 32 + tc] = o;
        return;
    }
    {                                     // cpH table (f16)
        const int tid = (b - 2048) * 256 + t;
        if (tid < NEURONS * 15) {
            const int n = tid / 15, ii = tid % 15;
            const float s = spb[n];
            f16x4 c;
            c[0] = (f16)(coeff[n * 18 + ii]     + s);
            c[1] = (f16)(coeff[n * 18 + ii + 1] + s);
            c[2] = (f16)(coeff[n * 18 + ii + 2] + s);
            c[3] = (f16)(coeff[n * 18 + ii + 3] + s);
            *(f16x4*)&cpH[(size_t)tid * 4] = c;
        }
    }
}

// ===========================================================================
// gemm1: h(f16) = x @ W1 + b1, BM=128 BN=64 BK=64, global_load_lds(16B),
// linear LDS [row][64], dbuf, 1 barrier/step (proven R7/R9 structure).
// Partial min/max stores: pmin/pmax[(n0/64)*2 + wn][row]  (32 partials/row).
// ===========================================================================
__global__ __launch_bounds__(256) void k_gemm1(
    const f16* __restrict__ A, const f16* __restrict__ Bt,
    const float* __restrict__ b1, f16* __restrict__ h,
    float* __restrict__ pmin, float* __restrict__ pmax)
{
    __shared__ f16 lds[2][(128 + 64) * 64];   // 48 KB

    const int t    = threadIdx.x;
    const int lane = t & 63, l15 = lane & 15, lhi = lane >> 4;
    const int wid  = t >> 6;
    const int wm   = wid >> 1, wn = wid & 1;

    const int flat = blockIdx.y * gridDim.x + blockIdx.x;   // 512 blocks
    const int swz  = (flat & 7) * 64 + (flat >> 3);
    const int m0   = (swz >> 4) * 128;
    const int n0   = (swz & 15) * 64;

    auto stage = [&](int buf, int kt) {
        f16* base = &lds[buf][0];
#pragma unroll
        for (int j = 0; j < 4; ++j) {
            int c = wid * 4 + j;
            const f16* g = A + (size_t)(m0 + c * 8 + (lane >> 3)) * IN_DIM + kt + (lane & 7) * 8;
            __builtin_amdgcn_global_load_lds(
                (const __attribute__((address_space(1))) void*)g,
                (__attribute__((address_space(3))) void*)(base + c * 512), 16, 0, 0);
        }
#pragma unroll
        for (int j = 0; j < 2; ++j) {
            int c = wid * 2 + j;
            const f16* g = Bt + (size_t)(n0 + c * 8 + (lane >> 3)) * IN_DIM + kt + (lane & 7) * 8;
            __builtin_amdgcn_global_load_lds(
                (const __attribute__((address_space(1))) void*)g,
                (__attribute__((address_space(3))) void*)(base + 8192 + c * 512), 16, 0, 0);
        }
    };

    f32x4 acc[4][2];
#pragma unroll
    for (int i = 0; i < 4; ++i)
#pragma unroll
        for (int j = 0; j < 2; ++j) acc[i][j] = (f32x4)0.f;

    stage(0, 0);
    __syncthreads();

    int cur = 0;
    for (int tt = 0; tt < 8; ++tt) {                     // K = 512
        if (tt < 7) stage(cur ^ 1, (tt + 1) * 64);
        const f16* L = &lds[cur][0];
#pragma unroll
        for (int ks = 0; ks < 2; ++ks) {
            f16x8 bfr[2];
#pragma unroll
            for (int nj = 0; nj < 2; ++nj)
                bfr[nj] = *(const f16x8*)
                    &L[8192 + (wn * 32 + nj * 16 + l15) * 64 + ks * 32 + lhi * 8];
#pragma unroll
            for (int mi = 0; mi < 4; ++mi) {
                f16x8 afr = *(const f16x8*)
                    &L[(wm * 64 + mi * 16 + l15) * 64 + ks * 32 + lhi * 8];
#pragma unroll
                for (int nj = 0; nj < 2; ++nj)
                    acc[mi][nj] = __builtin_amdgcn_mfma_f32_16x16x32_f16(
                        afr, bfr[nj], acc[mi][nj], 0, 0, 0);
            }
        }
        __syncthreads();
        cur ^= 1;
    }

    const int nb2 = (n0 >> 6) * 2 + wn;                  // 0..31
#pragma unroll
    for (int mi = 0; mi < 4; ++mi) {
        const int row0 = m0 + wm * 64 + mi * 16 + lhi * 4;
        float vmn[4], vmx[4];
#pragma unroll
        for (int nj = 0; nj < 2; ++nj) {
            const int col = n0 + wn * 32 + nj * 16 + l15;
            const float bv = b1[col];
#pragma unroll
            for (int j = 0; j < 4; ++j) {
                f16 hv = (f16)(acc[mi][nj][j] + bv);
                h[(size_t)(row0 + j) * NEURONS + col] = hv;
                float vr = (float)hv;                    // min/max of ROUNDED value
                if (nj == 0) { vmn[j] = vr; vmx[j] = vr; }
                else { vmn[j] = fminf(vmn[j], vr); vmx[j] = fmaxf(vmx[j], vr); }
            }
        }
#pragma unroll
        for (int j = 0; j < 4; ++j) {
#pragma unroll
            for (int d = 1; d < 16; d <<= 1) {
                vmn[j] = fminf(vmn[j], __shfl_xor(vmn[j], d));
                vmx[j] = fmaxf(vmx[j], __shfl_xor(vmx[j], d));
            }
        }
        if (l15 == 0) {
#pragma unroll
            for (int j = 0; j < 4; ++j) {
                pmin[(size_t)nb2 * M_ROWS + row0 + j] = vmn[j];
                pmax[(size_t)nb2 * M_ROWS + row0 + j] = vmx[j];
            }
        }
    }
}

// ===========================================================================
// sp_gemm2 v2: out = relu(spline(norm(h)) @ W2 + b2)
// BM=64, BN=128, BK=64, grid 256 (1/CU), waves 2x2, 16 MFMA/step/wave.
// A-tile (64x64) spline-JIT'd into padded LDS [64][72] per K-step; B staged
// via global_load_lds from plain W2t [512][1024]. Dbuf, 1 barrier/step.
// XCD-chunked swizzle keeps each XCD inside one 128-col B-panel (L2 reuse).
// ===========================================================================
__global__ __launch_bounds__(256) void sp_gemm2(
    const f16* __restrict__ h, const float* __restrict__ pmin,
    const float* __restrict__ pmax, const f16* __restrict__ cpH,
    const f16* __restrict__ W2t, const float* __restrict__ b2,
    float* __restrict__ out)
{
    __shared__ __align__(16) f16 Bb[2][128 * 64];        // 32 KB
    __shared__ __align__(16) f16 Aa[2][64 * 72];         // 18 KB (padded)
    __shared__ float mnS[64], invS[64];

    const int t    = threadIdx.x;
    const int lane = t & 63, l15 = lane & 15, lhi = lane >> 4;
    const int wid  = t >> 6;
    const int wm   = wid >> 1, wn = wid & 1;

    // 256 blocks = 64 m-tiles x 4 n-tiles (n-major chunks of 64 -> per-XCD
    // chunk of 32 stays within one n-panel)
    const int flat = blockIdx.x;
    const int swz  = (flat & 7) * 32 + (flat >> 3);
    const int m0   = (swz & 63) * 64;
    const int n0   = (swz >> 6) * 128;

    auto stageB = [&](int bf, int tt) {
        f16* base = &Bb[bf][0];
#pragma unroll
        for (int j = 0; j < 4; ++j) {
            const int c = wid * 4 + j;                   // 16 chunks of 8 rows
            const f16* src = W2t + (size_t)(n0 + c * 8 + (lane >> 3)) * NEURONS
                             + tt * 64 + (lane & 7) * 8;
            __builtin_amdgcn_global_load_lds(
                (const __attribute__((address_space(1))) void*)src,
                (__attribute__((address_space(3))) void*)(base + c * 512), 16, 0, 0);
        }
    };

    auto splineA = [&](int bf, int tt) {
        const int r_  = t & 63;                          // row 0..63
        const int sg  = (t >> 6) * 16;                   // k-seg 0,16,32,48
        const float mn = mnS[r_], inv = invS[r_];
#pragma unroll
        for (int hf = 0; hf < 2; ++hf) {
            const int kg = tt * 64 + sg + hf * 8;
            f16x8 hv = *(const f16x8*)&h[(size_t)(m0 + r_) * NEURONS + kg];
            f16x8 o;
#pragma unroll
            for (int e = 0; e < 8; ++e) {
                const float u   = ((float)hv[e] - mn) * inv;
                const float t15 = u * 15.0f;
                int ii = (int)t15;
                ii = ii < 0 ? 0 : (ii > 14 ? 14 : ii);
                const float tl  = t15 - (float)ii;
                const float t2  = tl * tl, t3 = t2 * tl;
                const float omt = 1.0f - tl;
                const float b0  = omt * omt * omt * (1.0f / 6.0f);
                const float b3v = t3 * (1.0f / 6.0f);
                const float b1v = (4.0f / 6.0f) - t2 + 0.5f * t3;
                const float b2v = (1.0f / 6.0f) + 0.5f * (tl + t2 - t3);
                const f16x4 c   = *(const f16x4*)&cpH[((size_t)(kg + e) * 15 + ii) * 4];
                o[e] = (f16)((float)c[0] * b0 + (float)c[1] * b1v
                           + (float)c[2] * b2v + (float)c[3] * b3v);
            }
            *(f16x8*)&Aa[bf][r_ * 72 + sg + hf * 8] = o;
        }
    };

    // ---- prologue: reduce 32 partials -> mn/inv for rows m0..m0+63 --------
    stageB(0, 0);
    if (t < 64) {
        const int row = m0 + t;
        float a = pmin[row], b = pmax[row];
#pragma unroll
        for (int p = 1; p < 32; ++p) {
            a = fminf(a, pmin[(size_t)p * M_ROWS + row]);
            b = fmaxf(b, pmax[(size_t)p * M_ROWS + row]);
        }
        mnS[t] = a;
        invS[t] = 1.0f / (b - a + 1e-8f);
    }
    __syncthreads();          // mnS ready; stageB(0) drained (vmcnt 0)
    splineA(0, 0);
    __syncthreads();          // Aa[0] visible

    f32x4 acc[2][4];
#pragma unroll
    for (int i = 0; i < 2; ++i)
#pragma unroll
        for (int j = 0; j < 4; ++j) acc[i][j] = (f32x4)0.f;

    int cur = 0;
    for (int tt = 0; tt < 16; ++tt) {                    // K = 1024
        if (tt < 15) {
            stageB(cur ^ 1, tt + 1);
            splineA(cur ^ 1, tt + 1);
        }
#pragma unroll
        for (int ks = 0; ks < 2; ++ks) {
            f16x8 bfr[4];
#pragma unroll
            for (int nj = 0; nj < 4; ++nj)
                bfr[nj] = *(const f16x8*)
                    &Bb[cur][(wn * 64 + nj * 16 + l15) * 64 + ks * 32 + lhi * 8];
#pragma unroll
            for (int mi = 0; mi < 2; ++mi) {
                f16x8 afr = *(const f16x8*)
                    &Aa[cur][(wm * 32 + mi * 16 + l15) * 72 + ks * 32 + lhi * 8];
#pragma unroll
                for (int nj = 0; nj < 4; ++nj)
                    acc[mi][nj] = __builtin_amdgcn_mfma_f32_16x16x32_f16(
                        afr, bfr[nj], acc[mi][nj], 0, 0, 0);
            }
        }
        __syncthreads();
        cur ^= 1;
    }

    // epilogue: col = l15, row = lhi*4 + j
#pragma unroll
    for (int mi = 0; mi < 2; ++mi) {
        const int row0 = m0 + wm * 32 + mi * 16 + lhi * 4;
#pragma unroll
        for (int nj = 0; nj < 4; ++nj) {
            const int col = n0 + wn * 64 + nj * 16 + l15;
            const float bv = b2[col];
#pragma unroll
            for (int j = 0; j < 4; ++j)
                out[(size_t)(row0 + j) * OUT_DIM + col] =
                    fmaxf(acc[mi][nj][j] + bv, 0.0f);
        }
    }
}

// ===========================================================================
extern "C" void kernel_launch(void* const* d_in, const int* in_sizes, int n_in,
                              void* d_out, int out_size, void* d_ws, size_t ws_size,
                              hipStream_t stream)
{
    const float* x     = (const float*)d_in[0];
    const float* W1    = (const float*)d_in[1];
    const float* b1    = (const float*)d_in[2];
    const float* coeff = (const float*)d_in[3];
    const float* spb   = (const float*)d_in[4];
    const float* W2    = (const float*)d_in[5];
    const float* b2    = (const float*)d_in[6];
    float* out = (float*)d_out;

    char* ws = (char*)d_ws;
    f16*   h    = (f16*)ws;                                   //  8 MB [4096][1024]
    f16*   xh   = (f16*)(ws + ( 8u << 20));                   //  4 MB [4096][512]
    f16*   W1t  = (f16*)(ws + (12u << 20));                   //  1 MB [1024][512]
    f16*   W2t  = (f16*)(ws + (13u << 20));                   //  1 MB [512][1024]
    float* pmin = (float*)(ws + (14u << 20));                 // 512 KB [32][4096]
    float* pmax = (float*)(ws + (14u << 20) + (512u << 10));  // 512 KB
    f16*   cpH  = (f16*)(ws + (15u << 20));                   // 120 KB [1024][15][4]

    prep<<<dim3(2108), 256, 0, stream>>>(x, xh, W1, W1t, W2, W2t, coeff, spb, cpH);

    k_gemm1<<<dim3(16, 32), 256, 0, stream>>>(xh, W1t, b1, h, pmin, pmax);

    sp_gemm2<<<dim3(256), 256, 0, stream>>>(h, pmin, pmax, cpH, W2t, b2, out);
}

// Round 11
// 47.984 us; speedup vs baseline: 1.7651x; 1.7651x over previous
//
#include <hip/hip_runtime.h>

#define M_ROWS  4096
#define IN_DIM  512
#define NEURONS 1024
#define OUT_DIM 512

typedef _Float16 f16;
typedef __attribute__((ext_vector_type(8))) _Float16 f16x8;
typedef __attribute__((ext_vector_type(4))) _Float16 f16x4;
typedef __attribute__((ext_vector_type(4))) float    f32x4;

// ===========================================================================
// prep:
//  [0,1024)    x f32 -> xh f16
//  [1024,1536) W1 [512][1024] -> W1t [1024][512] f16
//  [1536,2048) W2 [1024][512] -> W2t [512][1024] f16, pre-XOR-swizzled:
//              byte-in-row ^= ((n&7)<<4)   (rule #21: swizzle source + read)
//  [2048,2108) cpH[n][ii][4] f16 = coeff window + spb (partition of unity)
// ===========================================================================
__global__ __launch_bounds__(256) void prep(
    const float* __restrict__ x,  f16* __restrict__ xh,
    const float* __restrict__ W1, f16* __restrict__ W1t,
    const float* __restrict__ W2, f16* __restrict__ W2t,
    const float* __restrict__ coeff, const float* __restrict__ spb,
    f16* __restrict__ cpH)
{
    __shared__ float S[32][33];
    const int b = blockIdx.x, t = threadIdx.x;
    if (b < 1024) {
        int i = b * 256 + t;
        const float4* p = (const float4*)x;
        float4 a = p[i * 2], c = p[i * 2 + 1];
        f16x8 o = { (f16)a.x, (f16)a.y, (f16)a.z, (f16)a.w,
                    (f16)c.x, (f16)c.y, (f16)c.z, (f16)c.w };
        *(f16x8*)(xh + (size_t)i * 8) = o;
        return;
    }
    if (b < 1536) {                       // W1 transpose -> f16
        const int tile = b - 1024;
        const int tx = tile & 31, ty = tile >> 5;
        const int tr = t >> 3, tc = (t & 7) * 4;
        float4 v = *(const float4*)&W1[(size_t)(ty * 32 + tr) * NEURONS + tx * 32 + tc];
        S[tr][tc + 0] = v.x; S[tr][tc + 1] = v.y;
        S[tr][tc + 2] = v.z; S[tr][tc + 3] = v.w;
        __syncthreads();
        f16x4 o = {(f16)S[tc + 0][tr], (f16)S[tc + 1][tr],
                   (f16)S[tc + 2][tr], (f16)S[tc + 3][tr]};
        *(f16x4*)&W1t[(size_t)(tx * 32 + tr) * IN_DIM + ty * 32 + tc] = o;
        return;
    }
    if (b < 2048) {                       // W2 transpose -> f16, swizzled
        const int tile = b - 1536;
        const int nt = tile & 15, kt2 = tile >> 4;
        const int tr = t >> 3, tc = (t & 7) * 4;
        float4 v = *(const float4*)&W2[(size_t)(kt2 * 32 + tr) * OUT_DIM + nt * 32 + tc];
        S[tr][tc + 0] = v.x; S[tr][tc + 1] = v.y;
        S[tr][tc + 2] = v.z; S[tr][tc + 3] = v.w;
        __syncthreads();
        const int n = nt * 32 + tr;
        f16x4 o = {(f16)S[tc + 0][tr], (f16)S[tc + 1][tr],
                   (f16)S[tc + 2][tr], (f16)S[tc + 3][tr]};
        const int kbyte = ((kt2 * 32 + tc) * 2) ^ ((n & 7) << 4);
        *(f16x4*)((char*)W2t + (size_t)n * 2048 + kbyte) = o;
        return;
    }
    {                                     // cpH table (f16)
        const int tid = (b - 2048) * 256 + t;
        if (tid < NEURONS * 15) {
            const int n = tid / 15, ii = tid % 15;
            const float s = spb[n];
            f16x4 c;
            c[0] = (f16)(coeff[n * 18 + ii]     + s);
            c[1] = (f16)(coeff[n * 18 + ii + 1] + s);
            c[2] = (f16)(coeff[n * 18 + ii + 2] + s);
            c[3] = (f16)(coeff[n * 18 + ii + 3] + s);
            *(f16x4*)&cpH[(size_t)tid * 4] = c;
        }
    }
}

// ===========================================================================
// gemm1: h(f16) = x @ W1 + b1, BM=128 BN=64 BK=64, global_load_lds(16B),
// linear LDS [row][64], dbuf, 1 barrier/step (proven R7/R9 structure).
// Partial min/max stores: pmin/pmax[(n0/64)*2 + wn][row]  (32 partials/row).
// ===========================================================================
__global__ __launch_bounds__(256) void k_gemm1(
    const f16* __restrict__ A, const f16* __restrict__ Bt,
    const float* __restrict__ b1, f16* __restrict__ h,
    float* __restrict__ pmin, float* __restrict__ pmax)
{
    __shared__ f16 lds[2][(128 + 64) * 64];   // 48 KB

    const int t    = threadIdx.x;
    const int lane = t & 63, l15 = lane & 15, lhi = lane >> 4;
    const int wid  = t >> 6;
    const int wm   = wid >> 1, wn = wid & 1;

    const int flat = blockIdx.y * gridDim.x + blockIdx.x;   // 512 blocks
    const int swz  = (flat & 7) * 64 + (flat >> 3);
    const int m0   = (swz >> 4) * 128;
    const int n0   = (swz & 15) * 64;

    auto stage = [&](int buf, int kt) {
        f16* base = &lds[buf][0];
#pragma unroll
        for (int j = 0; j < 4; ++j) {
            int c = wid * 4 + j;
            const f16* g = A + (size_t)(m0 + c * 8 + (lane >> 3)) * IN_DIM + kt + (lane & 7) * 8;
            __builtin_amdgcn_global_load_lds(
                (const __attribute__((address_space(1))) void*)g,
                (__attribute__((address_space(3))) void*)(base + c * 512), 16, 0, 0);
        }
#pragma unroll
        for (int j = 0; j < 2; ++j) {
            int c = wid * 2 + j;
            const f16* g = Bt + (size_t)(n0 + c * 8 + (lane >> 3)) * IN_DIM + kt + (lane & 7) * 8;
            __builtin_amdgcn_global_load_lds(
                (const __attribute__((address_space(1))) void*)g,
                (__attribute__((address_space(3))) void*)(base + 8192 + c * 512), 16, 0, 0);
        }
    };

    f32x4 acc[4][2];
#pragma unroll
    for (int i = 0; i < 4; ++i)
#pragma unroll
        for (int j = 0; j < 2; ++j) acc[i][j] = (f32x4)0.f;

    stage(0, 0);
    __syncthreads();

    int cur = 0;
    for (int tt = 0; tt < 8; ++tt) {                     // K = 512
        if (tt < 7) stage(cur ^ 1, (tt + 1) * 64);
        const f16* L = &lds[cur][0];
#pragma unroll
        for (int ks = 0; ks < 2; ++ks) {
            f16x8 bfr[2];
#pragma unroll
            for (int nj = 0; nj < 2; ++nj)
                bfr[nj] = *(const f16x8*)
                    &L[8192 + (wn * 32 + nj * 16 + l15) * 64 + ks * 32 + lhi * 8];
#pragma unroll
            for (int mi = 0; mi < 4; ++mi) {
                f16x8 afr = *(const f16x8*)
                    &L[(wm * 64 + mi * 16 + l15) * 64 + ks * 32 + lhi * 8];
#pragma unroll
                for (int nj = 0; nj < 2; ++nj)
                    acc[mi][nj] = __builtin_amdgcn_mfma_f32_16x16x32_f16(
                        afr, bfr[nj], acc[mi][nj], 0, 0, 0);
            }
        }
        __syncthreads();
        cur ^= 1;
    }

    const int nb2 = (n0 >> 6) * 2 + wn;                  // 0..31
#pragma unroll
    for (int mi = 0; mi < 4; ++mi) {
        const int row0 = m0 + wm * 64 + mi * 16 + lhi * 4;
        float vmn[4], vmx[4];
#pragma unroll
        for (int nj = 0; nj < 2; ++nj) {
            const int col = n0 + wn * 32 + nj * 16 + l15;
            const float bv = b1[col];
#pragma unroll
            for (int j = 0; j < 4; ++j) {
                f16 hv = (f16)(acc[mi][nj][j] + bv);
                h[(size_t)(row0 + j) * NEURONS + col] = hv;
                float vr = (float)hv;                    // min/max of ROUNDED value
                if (nj == 0) { vmn[j] = vr; vmx[j] = vr; }
                else { vmn[j] = fminf(vmn[j], vr); vmx[j] = fmaxf(vmx[j], vr); }
            }
        }
#pragma unroll
        for (int j = 0; j < 4; ++j) {
#pragma unroll
            for (int d = 1; d < 16; d <<= 1) {
                vmn[j] = fminf(vmn[j], __shfl_xor(vmn[j], d));
                vmx[j] = fmaxf(vmx[j], __shfl_xor(vmx[j], d));
            }
        }
        if (l15 == 0) {
#pragma unroll
            for (int j = 0; j < 4; ++j) {
                pmin[(size_t)nb2 * M_ROWS + row0 + j] = vmn[j];
                pmax[(size_t)nb2 * M_ROWS + row0 + j] = vmx[j];
            }
        }
    }
}

// ===========================================================================
// sp_gemm2 v3: out = relu(spline(norm(h)) @ W2 + b2)
// BM=32, BN=128, BK=64, grid 512 (2 blocks/CU), waves 2(m)x2(n).
// Per K-step s:  cp-slice s (7.7 KB) lives in LDS (staged 2 steps ahead so
// the end-of-step barrier drains it); 32x64 A-tile spline-JIT'd into padded
// LDS (8 evals/thread, gathers hit LDS not L2); B staged via global_load_lds
// from pre-swizzled W2t, XOR applied on ds_read. Everything dbuf by (s&1).
// ===========================================================================
__global__ __launch_bounds__(256) void sp_gemm2(
    const f16* __restrict__ h, const float* __restrict__ pmin,
    const float* __restrict__ pmax, const f16* __restrict__ cpH,
    const f16* __restrict__ W2t, const float* __restrict__ b2,
    float* __restrict__ out)
{
    __shared__ __align__(16) f16 Bb[2][128 * 64];        // 32 KB
    __shared__ __align__(16) f16 Aa[2][32 * 72];         // 9 KB (padded)
    __shared__ __align__(16) f16 cpS[2][4096];           // 16 KB (8192 B each)
    __shared__ float mnS[32], invS[32];

    const int t    = threadIdx.x;
    const int lane = t & 63, l15 = lane & 15, lhi = lane >> 4;
    const int wid  = t >> 6;
    const int wm   = wid & 1, wn = wid >> 1;

    // 512 blocks = 128 m-tiles x 4 n-panels; each XCD: 64 consecutive
    // m-tiles inside ONE n-panel (B panel 256 KB + h slice 4 MB L2-resident)
    const int flat = blockIdx.x;
    const int swz  = (flat & 7) * 64 + (flat >> 3);
    const int m0   = (swz & 127) * 32;
    const int n0   = (swz >> 7) * 128;

    auto stageB = [&](int s) {
        f16* base = &Bb[s & 1][0];
#pragma unroll
        for (int j = 0; j < 4; ++j) {
            const int c = wid * 4 + j;                   // 16 chunks of 8 rows
            const char* src = (const char*)W2t + (size_t)(n0 + c * 8 + (lane >> 3)) * 2048
                              + s * 128 + (lane & 7) * 16;
            __builtin_amdgcn_global_load_lds(
                (const __attribute__((address_space(1))) void*)src,
                (__attribute__((address_space(3))) void*)((char*)base + c * 1024),
                16, 0, 0);
        }
    };
    auto stageCp = [&](int s) {
        // slice s = cpH bytes [s*7680, s*7680+7680); load 8192 B (pad OK)
        const char* src = (const char*)cpH + (size_t)s * 7680 + (wid * 64 + lane) * 16;
        char* base = (char*)&cpS[s & 1][0];
        __builtin_amdgcn_global_load_lds(
            (const __attribute__((address_space(1))) void*)src,
            (__attribute__((address_space(3))) void*)(base + wid * 1024), 16, 0, 0);
        __builtin_amdgcn_global_load_lds(
            (const __attribute__((address_space(1))) void*)(src + 4096),
            (__attribute__((address_space(3))) void*)(base + 4096 + wid * 1024), 16, 0, 0);
    };
    auto splineA = [&](int s) {
        const int r_  = t >> 3;                          // 0..31
        const int ks8 = (t & 7) * 8;                     // 0..56
        const int kg  = s * 64 + ks8;
        f16x8 hv = *(const f16x8*)&h[(size_t)(m0 + r_) * NEURONS + kg];
        const float mn = mnS[r_], inv = invS[r_];
        const f16* cps = &cpS[s & 1][0];
        f16x8 o;
#pragma unroll
        for (int e = 0; e < 8; ++e) {
            const float u   = ((float)hv[e] - mn) * inv;
            const float t15 = u * 15.0f;
            int ii = (int)t15;
            ii = ii < 0 ? 0 : (ii > 14 ? 14 : ii);
            const float tl  = t15 - (float)ii;
            const float t2  = tl * tl, t3 = t2 * tl;
            const float omt = 1.0f - tl;
            const float b0  = omt * omt * omt * (1.0f / 6.0f);
            const float b3v = t3 * (1.0f / 6.0f);
            const float b1v = (4.0f / 6.0f) - t2 + 0.5f * t3;
            const float b2v = (1.0f / 6.0f) + 0.5f * (tl + t2 - t3);
            const f16x4 c   = *(const f16x4*)&cps[((ks8 + e) * 15 + ii) * 4];
            o[e] = (f16)((float)c[0] * b0 + (float)c[1] * b1v
                       + (float)c[2] * b2v + (float)c[3] * b3v);
        }
        *(f16x8*)&Aa[s & 1][r_ * 72 + ks8] = o;
    };

    // ---- prologue --------------------------------------------------------
    stageCp(0); stageCp(1); stageB(0);
    if (t < 32) {
        const int row = m0 + t;
        float a = pmin[row], b = pmax[row];
#pragma unroll
        for (int p = 1; p < 32; ++p) {
            a = fminf(a, pmin[(size_t)p * M_ROWS + row]);
            b = fmaxf(b, pmax[(size_t)p * M_ROWS + row]);
        }
        mnS[t] = a;
        invS[t] = 1.0f / (b - a + 1e-8f);
    }
    __syncthreads();          // DMAs drained; mnS visible
    splineA(0);
    __syncthreads();          // Aa[0] visible

    f32x4 acc[4];
#pragma unroll
    for (int j = 0; j < 4; ++j) acc[j] = (f32x4)0.f;

    for (int s = 0; s < 16; ++s) {                       // K = 1024
        if (s + 1 < 16) stageB(s + 1);
        if (s + 2 < 16) stageCp(s + 2);
        if (s + 1 < 16) splineA(s + 1);                  // reads cpS[(s+1)&1], drained
        const char* B_ = (const char*)&Bb[s & 1][0];
        const f16*  A_ = &Aa[s & 1][0];
#pragma unroll
        for (int ks = 0; ks < 2; ++ks) {
            f16x8 afr = *(const f16x8*)&A_[(wm * 16 + l15) * 72 + ks * 32 + lhi * 8];
#pragma unroll
            for (int nj = 0; nj < 4; ++nj) {
                const int cl = wn * 64 + nj * 16 + l15;
                const int kb = (ks * 64 + lhi * 16) ^ ((cl & 7) << 4);
                f16x8 bfr = *(const f16x8*)(B_ + (size_t)cl * 128 + kb);
                acc[nj] = __builtin_amdgcn_mfma_f32_16x16x32_f16(afr, bfr, acc[nj], 0, 0, 0);
            }
        }
        __syncthreads();
    }

    // epilogue: col = l15, row = lhi*4 + j
    const int row0 = m0 + wm * 16 + lhi * 4;
#pragma unroll
    for (int nj = 0; nj < 4; ++nj) {
        const int col = n0 + wn * 64 + nj * 16 + l15;
        const float bv = b2[col];
#pragma unroll
        for (int j = 0; j < 4; ++j)
            out[(size_t)(row0 + j) * OUT_DIM + col] =
                fmaxf(acc[nj][j] + bv, 0.0f);
    }
}

// ===========================================================================
extern "C" void kernel_launch(void* const* d_in, const int* in_sizes, int n_in,
                              void* d_out, int out_size, void* d_ws, size_t ws_size,
                              hipStream_t stream)
{
    const float* x     = (const float*)d_in[0];
    const float* W1    = (const float*)d_in[1];
    const float* b1    = (const float*)d_in[2];
    const float* coeff = (const float*)d_in[3];
    const float* spb   = (const float*)d_in[4];
    const float* W2    = (const float*)d_in[5];
    const float* b2    = (const float*)d_in[6];
    float* out = (float*)d_out;

    char* ws = (char*)d_ws;
    f16*   h    = (f16*)ws;                                   //  8 MB [4096][1024]
    f16*   xh   = (f16*)(ws + ( 8u << 20));                   //  4 MB [4096][512]
    f16*   W1t  = (f16*)(ws + (12u << 20));                   //  1 MB [1024][512]
    f16*   W2t  = (f16*)(ws + (13u << 20));                   //  1 MB [512][1024] swz
    float* pmin = (float*)(ws + (14u << 20));                 // 512 KB [32][4096]
    float* pmax = (float*)(ws + (14u << 20) + (512u << 10));  // 512 KB
    f16*   cpH  = (f16*)(ws + (15u << 20));                   // 120 KB [1024][15][4]

    prep<<<dim3(2108), 256, 0, stream>>>(x, xh, W1, W1t, W2, W2t, coeff, spb, cpH);

    k_gemm1<<<dim3(16, 32), 256, 0, stream>>>(xh, W1t, b1, h, pmin, pmax);

    sp_gemm2<<<dim3(512), 256, 0, stream>>>(h, pmin, pmax, cpH, W2t, b2, out);
}